// Round 3
// baseline (402.641 us; speedup 1.0000x reference)
//
#include <hip/hip_runtime.h>
#include <hip/hip_bf16.h>
#include <stdint.h>

typedef unsigned short u16;
typedef __bf16 v8bf __attribute__((ext_vector_type(8)));
typedef float f32x4 __attribute__((ext_vector_type(4)));

// ws byte offsets (total ~2.2 MB)
#define WS_WB    0u          // float[256]
#define WS_CACC  4096u       // float[65536]   (256 KB) ends 266240
#define WS_WIHB  270336u     // u16[196608]    (384 KB) ends 663552
#define WS_WHHB  663552u     // u16[196608]    (384 KB) ends 1056768
#define WS_W2B   1056768u    // u16[65536]     (128 KB) ends 1187840
#define WS_A     1187840u    // float[262144]  (1 MB)   ends 2236416

// out (fp32) element offsets
#define OUT_STAB   0
#define OUT_EMER   3584
#define OUT_DECAY  7168
#define OUT_CAUSAL 10752
#define OUT_EVO    76288

__device__ __forceinline__ u16 f2bfu(float f){
    union { float f; uint32_t u; } v; v.f = f;
    uint32_t u = v.u;
    return (u16)((u + 0x7fffu + ((u >> 16) & 1u)) >> 16);
}
__device__ __forceinline__ float sigmoidf_fast(float x){
    float e = __builtin_amdgcn_exp2f(-1.4426950408889634f * x);
    return __builtin_amdgcn_rcpf(1.0f + e);
}
__device__ __forceinline__ float tanhf_fast(float x){
    float e = __builtin_amdgcn_exp2f(-2.8853900817779268f * x);
    return __builtin_amdgcn_rcpf(1.0f + e) * 2.0f - 1.0f;
}
__device__ __forceinline__ f32x4 mfma16(v8bf a, v8bf b, f32x4 c){
    return __builtin_amdgcn_mfma_f32_16x16x32_bf16(a, b, c, 0, 0, 0);
}
__device__ __forceinline__ v8bf cvt8(const float* p){
    float4 a = *(const float4*)p;
    float4 b = *(const float4*)(p + 4);
    v8bf r;
    r[0] = (__bf16)a.x; r[1] = (__bf16)a.y; r[2] = (__bf16)a.z; r[3] = (__bf16)a.w;
    r[4] = (__bf16)b.x; r[5] = (__bf16)b.y; r[6] = (__bf16)b.z; r[7] = (__bf16)b.w;
    return r;
}

// ---------------- prep: bf16 weight copies + wb + zero cacc ----------------
__global__ void k_prep(const float* __restrict__ Wih, const float* __restrict__ Whh,
                       const float* __restrict__ W2,  const float* __restrict__ W1,
                       u16* __restrict__ wihb, u16* __restrict__ whhb,
                       u16* __restrict__ w2b, float* __restrict__ wb,
                       float* __restrict__ cacc){
    int idx = blockIdx.x * 256 + threadIdx.x;   // 2049 blocks
    if (idx < 196608) {
        wihb[idx] = f2bfu(Wih[idx]);
    } else if (idx < 393216) {
        int i = idx - 196608; whhb[i] = f2bfu(Whh[i]);
    } else if (idx < 458752) {
        int i = idx - 393216; w2b[i] = f2bfu(W2[i]);
    } else if (idx < 459008) {
        int o = idx - 458752;
        float s = 0.f;
        const float4* p = (const float4*)&W1[o * 512 + 256];
        for (int j = 0; j < 64; j++){
            float4 v = p[j];
            s += v.x + v.y + v.z + v.w;
        }
        wb[o] = s;
    } else if (idx < 524544) {
        cacc[idx - 459008] = 0.f;
    }
}

// ---------------- A = src @ W1a^T + b1 via MFMA ----------------
__global__ __launch_bounds__(256) void k_Agemm(
        const float* __restrict__ src, const float* __restrict__ W1,
        const float* __restrict__ b1, float* __restrict__ A){
    const int bs0 = blockIdx.x * 16;
    const int tid = threadIdx.x, lane = tid & 63, w = tid >> 6;
    const int l15 = lane & 15, quad = lane >> 4;

    v8bf xa[8];
    for (int k = 0; k < 8; k++)
        xa[k] = cvt8(&src[(bs0 + l15) * 256 + k * 32 + quad * 8]);

    f32x4 acc[4];
    for (int nt = 0; nt < 4; nt++) acc[nt] = (f32x4){0.f, 0.f, 0.f, 0.f};
    for (int k = 0; k < 8; k++){
        int d0 = k * 32 + quad * 8;
        for (int nt = 0; nt < 4; nt++){
            int o = w * 64 + nt * 16 + l15;
            v8bf bfr = cvt8(&W1[o * 512 + d0]);
            acc[nt] = mfma16(xa[k], bfr, acc[nt]);
        }
    }
    for (int nt = 0; nt < 4; nt++){
        int o = w * 64 + nt * 16 + l15;
        float bb = b1[o];
        for (int r = 0; r < 4; r++)
            A[(bs0 + quad * 4 + r) * 256 + o] = acc[nt][r] + bb;
    }
}

// ---------------- stability / emergence / decay (fp32 out) ----------------
__global__ void k_metrics(const float* __restrict__ feat, float* __restrict__ out){
    const int bid = blockIdx.x;            // 3584 = 7*512
    const int l = bid >> 9, s = bid & 511;
    const int lane = threadIdx.x;          // 64
    float stab = 0.f, emer = 0.f;
    for (int b = 0; b < 2; b++){
        const float* p = feat + ((size_t)((b * 8 + l) * 512 + s)) * 256;
        const float* n = feat + ((size_t)((b * 8 + l + 1) * 512 + s)) * 256;
        float4 pv = *(const float4*)(p + lane * 4);
        float4 nv = *(const float4*)(n + lane * 4);
        float dot = pv.x * nv.x + pv.y * nv.y + pv.z * nv.z + pv.w * nv.w;
        float na2 = pv.x * pv.x + pv.y * pv.y + pv.z * pv.z + pv.w * pv.w;
        float nb2 = nv.x * nv.x + nv.y * nv.y + nv.z * nv.z + nv.w * nv.w;
        float ap = ((pv.x > 0.1f) ? 1.f : 0.f) + ((pv.y > 0.1f) ? 1.f : 0.f)
                 + ((pv.z > 0.1f) ? 1.f : 0.f) + ((pv.w > 0.1f) ? 1.f : 0.f);
        float an = ((nv.x > 0.1f) ? 1.f : 0.f) + ((nv.y > 0.1f) ? 1.f : 0.f)
                 + ((nv.z > 0.1f) ? 1.f : 0.f) + ((nv.w > 0.1f) ? 1.f : 0.f);
        for (int off = 32; off > 0; off >>= 1){
            dot += __shfl_xor(dot, off);
            na2 += __shfl_xor(na2, off);
            nb2 += __shfl_xor(nb2, off);
            ap  += __shfl_xor(ap,  off);
            an  += __shfl_xor(an,  off);
        }
        float na = fmaxf(__builtin_sqrtf(na2), 1e-8f);
        float nb = fmaxf(__builtin_sqrtf(nb2), 1e-8f);
        stab += dot / (na * nb);
        emer += (an - ap);
    }
    if (lane == 0){
        int o = l * 512 + s;
        float e = emer * 0.5f * (1.0f / 256.0f);
        out[OUT_STAB  + o] = stab * 0.5f;
        out[OUT_EMER  + o] = e;
        out[OUT_DECAY + o] = -e;
    }
}

// ---------------- causal main: atomic accumulate into cacc ----------------
__global__ __launch_bounds__(256) void k_causal(
        const float* __restrict__ Aws, const float* __restrict__ wbws,
        const u16* __restrict__ w2b, const float* __restrict__ tgt,
        const float* __restrict__ b2, float* __restrict__ cacc){
    const int bid = blockIdx.x;
    const int chunk = bid >> 2, q = bid & 3;
    const int i0 = (q & 1) * 128, p0 = (q >> 1) * 128;
    const int tid = threadIdx.x, lane = tid & 63, wid = tid >> 6;
    const int wrow = wid & 1, wcol = wid >> 1;
    const int l15 = lane & 15, quad = lane >> 4;

    __shared__ u16  w2s[128 * 264];
    __shared__ float a_s[256];
    __shared__ float wb_s[256];
    __shared__ float t_s[128];

    {
        int r = tid >> 1, half = tid & 1;
        const uint4* gsrc = (const uint4*)&w2b[(p0 + r) * 256 + half * 128];
        uint4* ldst = (uint4*)&w2s[r * 264 + half * 128];
        for (int j = 0; j < 16; j++) ldst[j] = gsrc[j];
    }
    wb_s[tid] = wbws[tid];

    float bb[4];
    for (int nt = 0; nt < 4; nt++) bb[nt] = b2[p0 + wcol * 64 + nt * 16 + l15];

    f32x4 sig[4][4];
    for (int mt = 0; mt < 4; mt++) for (int nt = 0; nt < 4; nt++)
        sig[mt][nt] = (f32x4){0.f, 0.f, 0.f, 0.f};

    const int ibl = wrow * 64;

    for (int ss = 0; ss < 8; ss++){
        const int bs = chunk * 8 + ss;
        __syncthreads();
        a_s[tid] = Aws[bs * 256 + tid];
        if (tid < 128) t_s[tid] = tgt[bs * 256 + i0 + tid];
        __syncthreads();

        float tv[4];
        for (int mt = 0; mt < 4; mt++) tv[mt] = t_s[ibl + mt * 16 + l15];

        f32x4 acc[4][4];
        for (int mt = 0; mt < 4; mt++) for (int nt = 0; nt < 4; nt++)
            acc[mt][nt] = (f32x4){0.f, 0.f, 0.f, 0.f};

        for (int k = 0; k < 8; k++){
            const int o0 = k * 32 + quad * 8;
            float4 a0 = *(const float4*)&a_s[o0];
            float4 a1 = *(const float4*)&a_s[o0 + 4];
            float4 w0 = *(const float4*)&wb_s[o0];
            float4 w1v = *(const float4*)&wb_s[o0 + 4];
            v8bf bfr[4];
            for (int nt = 0; nt < 4; nt++){
                int pl = wcol * 64 + nt * 16 + l15;
                bfr[nt] = *(const v8bf*)&w2s[pl * 264 + o0];
            }
            for (int mt = 0; mt < 4; mt++){
                float t = tv[mt];
                float e0 = fmaxf(fmaf(t, w0.x,  a0.x), 0.f);
                float e1 = fmaxf(fmaf(t, w0.y,  a0.y), 0.f);
                float e2 = fmaxf(fmaf(t, w0.z,  a0.z), 0.f);
                float e3 = fmaxf(fmaf(t, w0.w,  a0.w), 0.f);
                float e4 = fmaxf(fmaf(t, w1v.x, a1.x), 0.f);
                float e5 = fmaxf(fmaf(t, w1v.y, a1.y), 0.f);
                float e6 = fmaxf(fmaf(t, w1v.z, a1.z), 0.f);
                float e7 = fmaxf(fmaf(t, w1v.w, a1.w), 0.f);
                v8bf afr;
                afr[0] = (__bf16)e0; afr[1] = (__bf16)e1;
                afr[2] = (__bf16)e2; afr[3] = (__bf16)e3;
                afr[4] = (__bf16)e4; afr[5] = (__bf16)e5;
                afr[6] = (__bf16)e6; afr[7] = (__bf16)e7;
                for (int nt = 0; nt < 4; nt++)
                    acc[mt][nt] = mfma16(afr, bfr[nt], acc[mt][nt]);
            }
        }
        for (int mt = 0; mt < 4; mt++)
            for (int nt = 0; nt < 4; nt++)
                for (int r = 0; r < 4; r++)
                    sig[mt][nt][r] += sigmoidf_fast(acc[mt][nt][r] + bb[nt]);
    }

    for (int mt = 0; mt < 4; mt++)
        for (int r = 0; r < 4; r++){
            int i = i0 + ibl + mt * 16 + quad * 4 + r;
            for (int nt = 0; nt < 4; nt++){
                int p = p0 + wcol * 64 + nt * 16 + l15;
                atomicAdd(&cacc[i * 256 + p], sig[mt][nt][r]);
            }
        }
}

// ---------------- causal finalize ----------------
__global__ void k_cfinal(const float* __restrict__ cacc, float* __restrict__ out){
    const int idx4 = (blockIdx.x * 256 + threadIdx.x) * 4;  // 64 blocks
    float4 v = *(const float4*)&cacc[idx4];
    const float sc = 1.0f / 1024.0f;
    float4 r = {v.x * sc, v.y * sc, v.z * sc, v.w * sc};
    *(float4*)&out[OUT_CAUSAL + idx4] = r;
}

// ---------------- GRU persistent kernel: gx fused on the fly ----------------
__global__ __launch_bounds__(512) void k_gru(
        const float* __restrict__ feat, const u16* __restrict__ wihb,
        const u16* __restrict__ whhb, const float* __restrict__ bih,
        const float* __restrict__ bhh, float* __restrict__ out){
    const int n0 = blockIdx.x * 16;
    const int b = n0 >> 9, s0 = n0 & 511;
    const int tid = threadIdx.x, lane = tid & 63, wv = tid >> 6;  // 8 waves
    const int l15 = lane & 15, quad = lane >> 4;
    const int g0 = wv * 96;

    __shared__ float h_lds[16 * 260];
    __shared__ float g_lds[16 * 776];

    float bias[6];
    for (int nt = 0; nt < 6; nt++){
        int g = g0 + nt * 16 + l15;
        bias[nt] = bih[g] + bhh[g];
    }
    for (int e = tid; e < 16 * 260; e += 512) h_lds[e] = 0.f;
    __syncthreads();

    for (int t = 0; t < 8; t++){
        // A-fragments: x rows (all 16 seqs) for this timestep, and h rows
        const float* xp = feat + ((size_t)((b * 8 + t) * 512 + (s0 + l15))) * 256;
        v8bf xa[8], ha[8];
        for (int k = 0; k < 8; k++){
            int d0 = k * 32 + quad * 8;
            xa[k] = cvt8(xp + d0);
            ha[k] = cvt8(&h_lds[l15 * 260 + d0]);
        }
        f32x4 acc[6];
        for (int nt = 0; nt < 6; nt++) acc[nt] = (f32x4){0.f, 0.f, 0.f, 0.f};
        for (int k = 0; k < 8; k++){
            int d0 = k * 32 + quad * 8;
            for (int nt = 0; nt < 6; nt++){
                int g = g0 + nt * 16 + l15;
                v8bf bx = *(const v8bf*)&wihb[g * 256 + d0];
                v8bf bh = *(const v8bf*)&whhb[g * 256 + d0];
                acc[nt] = mfma16(xa[k], bx, acc[nt]);
                acc[nt] = mfma16(ha[k], bh, acc[nt]);
            }
        }
        for (int nt = 0; nt < 6; nt++){
            int g = g0 + nt * 16 + l15;
            for (int r = 0; r < 4; r++)
                g_lds[(quad * 4 + r) * 776 + g] = acc[nt][r] + bias[nt];
        }
        __syncthreads();
        {
            const int seq = tid >> 5;
            const int d0 = (tid & 31) * 8;
            const float* gp = &g_lds[seq * 776];
            float* hp = &h_lds[seq * 260 + d0];
            float hn[8];
            #pragma unroll
            for (int j = 0; j < 8; j++){
                int d = d0 + j;
                float r  = sigmoidf_fast(gp[d]);
                float z  = sigmoidf_fast(gp[256 + d]);
                float nn = tanhf_fast(fmaf(r, gp[512 + d] - 0.f, 0.f) * 0.f + gp[512 + d] * 0.f + 0.f); // placeholder (replaced below)
                (void)nn;
                hn[j] = 0.f;
            }
            // NOTE: n-gate needs gx3 + r*gh3, but g_lds holds gx3+gh3 summed.
            // Recompute properly: we stored SUM for gates r,z (correct), but for
            // the n-gate we must keep gx3 and gh3 separate. Handled via g2_lds.
            (void)hn;
        }
        __syncthreads();
    }
    (void)out;
}

extern "C" void kernel_launch(void* const* d_in, const int* in_sizes, int n_in,
                              void* d_out, int out_size, void* d_ws, size_t ws_size,
                              hipStream_t stream);

// ============================================================================
// The k_gru above has a structural flaw (n-gate needs gx3 and r*gh3 separately,
// not their sum). Correct version below; the flawed one is never launched.
// ============================================================================

__global__ __launch_bounds__(512) void k_gru2(
        const float* __restrict__ feat, const u16* __restrict__ wihb,
        const u16* __restrict__ whhb, const float* __restrict__ bih,
        const float* __restrict__ bhh, float* __restrict__ out){
    const int n0 = blockIdx.x * 16;
    const int b = n0 >> 9, s0 = n0 & 511;
    const int tid = threadIdx.x, lane = tid & 63, wv = tid >> 6;  // 8 waves
    const int l15 = lane & 15, quad = lane >> 4;
    const int g0 = wv * 96;

    __shared__ float h_lds[16 * 260];    // h state, fp32
    __shared__ float gx_lds[16 * 776];   // x-side pre-activations (+bih)
    __shared__ float gh_lds[16 * 776];   // h-side pre-activations (+bhh)

    float bx_bias[6], bh_bias[6];
    for (int nt = 0; nt < 6; nt++){
        int g = g0 + nt * 16 + l15;
        bx_bias[nt] = bih[g];
        bh_bias[nt] = bhh[g];
    }
    for (int e = tid; e < 16 * 260; e += 512) h_lds[e] = 0.f;
    __syncthreads();

    for (int t = 0; t < 8; t++){
        const float* xp = feat + ((size_t)((b * 8 + t) * 512 + (s0 + l15))) * 256;
        v8bf xa[8], ha[8];
        for (int k = 0; k < 8; k++){
            int d0 = k * 32 + quad * 8;
            xa[k] = cvt8(xp + d0);
            ha[k] = cvt8(&h_lds[l15 * 260 + d0]);
        }
        f32x4 accx[6], acch[6];
        for (int nt = 0; nt < 6; nt++){
            accx[nt] = (f32x4){0.f, 0.f, 0.f, 0.f};
            acch[nt] = (f32x4){0.f, 0.f, 0.f, 0.f};
        }
        for (int k = 0; k < 8; k++){
            int d0 = k * 32 + quad * 8;
            for (int nt = 0; nt < 6; nt++){
                int g = g0 + nt * 16 + l15;
                v8bf bx = *(const v8bf*)&wihb[g * 256 + d0];
                v8bf bh = *(const v8bf*)&whhb[g * 256 + d0];
                accx[nt] = mfma16(xa[k], bx, accx[nt]);
                acch[nt] = mfma16(ha[k], bh, acch[nt]);
            }
        }
        for (int nt = 0; nt < 6; nt++){
            int g = g0 + nt * 16 + l15;
            for (int r = 0; r < 4; r++){
                gx_lds[(quad * 4 + r) * 776 + g] = accx[nt][r] + bx_bias[nt];
                gh_lds[(quad * 4 + r) * 776 + g] = acch[nt][r] + bh_bias[nt];
            }
        }
        __syncthreads();
        {
            const int seq = tid >> 5;
            const int d0 = (tid & 31) * 8;
            const float* gx = &gx_lds[seq * 776];
            const float* gh = &gh_lds[seq * 776];
            float* hp = &h_lds[seq * 260 + d0];
            float hn[8];
            #pragma unroll
            for (int j = 0; j < 8; j++){
                int d = d0 + j;
                float r  = sigmoidf_fast(gx[d]       + gh[d]);
                float z  = sigmoidf_fast(gx[256 + d] + gh[256 + d]);
                float nn = tanhf_fast(fmaf(r, gh[512 + d], gx[512 + d]));
                float hnew = (1.f - z) * nn + z * hp[j];
                hp[j] = hnew;
                hn[j] = hnew;
            }
            float4 v0 = {hn[0], hn[1], hn[2], hn[3]};
            float4 v1 = {hn[4], hn[5], hn[6], hn[7]};
            size_t off = (size_t)OUT_EVO + ((size_t)(n0 + seq) * 8 + t) * 256 + d0;
            *(float4*)&out[off]     = v0;
            *(float4*)&out[off + 4] = v1;
        }
        __syncthreads();
    }
}

extern "C" void kernel_launch(void* const* d_in, const int* in_sizes, int n_in,
                              void* d_out, int out_size, void* d_ws, size_t ws_size,
                              hipStream_t stream){
    const float* feat = (const float*)d_in[0];
    const float* src  = (const float*)d_in[1];
    const float* tgt  = (const float*)d_in[2];
    const float* Wih  = (const float*)d_in[3];
    const float* Whh  = (const float*)d_in[4];
    const float* bih  = (const float*)d_in[5];
    const float* bhh  = (const float*)d_in[6];
    const float* W1   = (const float*)d_in[7];
    const float* b1   = (const float*)d_in[8];
    const float* W2   = (const float*)d_in[9];
    const float* b2   = (const float*)d_in[10];
    float* out = (float*)d_out;
    char* ws = (char*)d_ws;

    float* wb   = (float*)(ws + WS_WB);
    float* cacc = (float*)(ws + WS_CACC);
    u16*   wihb = (u16*)(ws + WS_WIHB);
    u16*   whhb = (u16*)(ws + WS_WHHB);
    u16*   w2b  = (u16*)(ws + WS_W2B);
    float* Aws  = (float*)(ws + WS_A);

    k_prep   <<<2049, 256, 0, stream>>>(Wih, Whh, W2, W1, wihb, whhb, w2b, wb, cacc);
    k_Agemm  <<<64,   256, 0, stream>>>(src, W1, b1, Aws);
    k_metrics<<<3584,  64, 0, stream>>>(feat, out);
    k_causal <<<512,  256, 0, stream>>>(Aws, wb, w2b, tgt, b2, cacc);
    k_cfinal <<<64,   256, 0, stream>>>(cacc, out);
    k_gru2   <<<64,   512, 0, stream>>>(feat, wihb, whhb, bih, bhh, out);
}

// Round 4
// 310.326 us; speedup vs baseline: 1.2975x; 1.2975x over previous
//
#include <hip/hip_runtime.h>
#include <hip/hip_bf16.h>
#include <stdint.h>

typedef unsigned short u16;
typedef __bf16 v8bf __attribute__((ext_vector_type(8)));
typedef float f32x4 __attribute__((ext_vector_type(4)));

// ws byte offsets (max ~58 MB — round-1 proved this footprint runs)
#define WS_WB    0u           // float[256]
#define WS_WIHB  4096u        // u16[196608] -> ends 397312
#define WS_WHHB  397312u      // u16[196608] -> ends 790528
#define WS_W2B   790528u      // u16[65536]  -> ends 921600
#define WS_A     921600u      // float[262144] -> ends 1970176
#define WS_GX    2097152u     // float[8192*768] = 25165824 B -> ends 27262976
#define WS_PART  27262976u    // float[128*65536] = 33554432 B -> ends 60817408

// out (fp32) element offsets
#define OUT_STAB   0
#define OUT_EMER   3584
#define OUT_DECAY  7168
#define OUT_CAUSAL 10752
#define OUT_EVO    76288

__device__ __forceinline__ u16 f2bfu(float f){
    union { float f; uint32_t u; } v; v.f = f;
    uint32_t u = v.u;
    return (u16)((u + 0x7fffu + ((u >> 16) & 1u)) >> 16);
}
__device__ __forceinline__ float sigmoidf_fast(float x){
    float e = __builtin_amdgcn_exp2f(-1.4426950408889634f * x);
    return __builtin_amdgcn_rcpf(1.0f + e);
}
__device__ __forceinline__ float tanhf_fast(float x){
    float e = __builtin_amdgcn_exp2f(-2.8853900817779268f * x);
    return __builtin_amdgcn_rcpf(1.0f + e) * 2.0f - 1.0f;
}
__device__ __forceinline__ f32x4 mfma16(v8bf a, v8bf b, f32x4 c){
    return __builtin_amdgcn_mfma_f32_16x16x32_bf16(a, b, c, 0, 0, 0);
}
__device__ __forceinline__ v8bf cvt8(const float* p){
    float4 a = *(const float4*)p;
    float4 b = *(const float4*)(p + 4);
    v8bf r;
    r[0] = (__bf16)a.x; r[1] = (__bf16)a.y; r[2] = (__bf16)a.z; r[3] = (__bf16)a.w;
    r[4] = (__bf16)b.x; r[5] = (__bf16)b.y; r[6] = (__bf16)b.z; r[7] = (__bf16)b.w;
    return r;
}

// ---------------- prep: bf16 weight copies + wb ----------------
__global__ void k_prep(const float* __restrict__ Wih, const float* __restrict__ Whh,
                       const float* __restrict__ W2,  const float* __restrict__ W1,
                       u16* __restrict__ wihb, u16* __restrict__ whhb,
                       u16* __restrict__ w2b, float* __restrict__ wb){
    int idx = blockIdx.x * 256 + threadIdx.x;   // 1793 blocks
    if (idx < 196608) {
        wihb[idx] = f2bfu(Wih[idx]);
    } else if (idx < 393216) {
        int i = idx - 196608; whhb[i] = f2bfu(Whh[i]);
    } else if (idx < 458752) {
        int i = idx - 393216; w2b[i] = f2bfu(W2[i]);
    } else if (idx < 459008) {
        int o = idx - 458752;
        float s = 0.f;
        const float4* p = (const float4*)&W1[o * 512 + 256];
        for (int j = 0; j < 64; j++){
            float4 v = p[j];
            s += v.x + v.y + v.z + v.w;
        }
        wb[o] = s;
    }
}

// ---------------- A = src @ W1a^T + b1 via MFMA ----------------
__global__ __launch_bounds__(256) void k_Agemm(
        const float* __restrict__ src, const float* __restrict__ W1,
        const float* __restrict__ b1, float* __restrict__ A){
    const int bs0 = blockIdx.x * 16;
    const int tid = threadIdx.x, lane = tid & 63, w = tid >> 6;
    const int l15 = lane & 15, quad = lane >> 4;

    v8bf xa[8];
    for (int k = 0; k < 8; k++)
        xa[k] = cvt8(&src[(bs0 + l15) * 256 + k * 32 + quad * 8]);

    f32x4 acc[4];
    for (int nt = 0; nt < 4; nt++) acc[nt] = (f32x4){0.f, 0.f, 0.f, 0.f};
    for (int k = 0; k < 8; k++){
        int d0 = k * 32 + quad * 8;
        for (int nt = 0; nt < 4; nt++){
            int o = w * 64 + nt * 16 + l15;
            v8bf bfr = cvt8(&W1[o * 512 + d0]);
            acc[nt] = mfma16(xa[k], bfr, acc[nt]);
        }
    }
    for (int nt = 0; nt < 4; nt++){
        int o = w * 64 + nt * 16 + l15;
        float bb = b1[o];
        for (int r = 0; r < 4; r++)
            A[(bs0 + quad * 4 + r) * 256 + o] = acc[nt][r] + bb;
    }
}

// ---------------- stability / emergence / decay ----------------
__global__ void k_metrics(const float* __restrict__ feat, float* __restrict__ out){
    const int bid = blockIdx.x;            // 3584 = 7*512
    const int l = bid >> 9, s = bid & 511;
    const int lane = threadIdx.x;          // 64
    float stab = 0.f, emer = 0.f;
    for (int b = 0; b < 2; b++){
        const float* p = feat + ((size_t)((b * 8 + l) * 512 + s)) * 256;
        const float* n = feat + ((size_t)((b * 8 + l + 1) * 512 + s)) * 256;
        float4 pv = *(const float4*)(p + lane * 4);
        float4 nv = *(const float4*)(n + lane * 4);
        float dot = pv.x * nv.x + pv.y * nv.y + pv.z * nv.z + pv.w * nv.w;
        float na2 = pv.x * pv.x + pv.y * pv.y + pv.z * pv.z + pv.w * pv.w;
        float nb2 = nv.x * nv.x + nv.y * nv.y + nv.z * nv.z + nv.w * nv.w;
        float ap = ((pv.x > 0.1f) ? 1.f : 0.f) + ((pv.y > 0.1f) ? 1.f : 0.f)
                 + ((pv.z > 0.1f) ? 1.f : 0.f) + ((pv.w > 0.1f) ? 1.f : 0.f);
        float an = ((nv.x > 0.1f) ? 1.f : 0.f) + ((nv.y > 0.1f) ? 1.f : 0.f)
                 + ((nv.z > 0.1f) ? 1.f : 0.f) + ((nv.w > 0.1f) ? 1.f : 0.f);
        for (int off = 32; off > 0; off >>= 1){
            dot += __shfl_xor(dot, off);
            na2 += __shfl_xor(na2, off);
            nb2 += __shfl_xor(nb2, off);
            ap  += __shfl_xor(ap,  off);
            an  += __shfl_xor(an,  off);
        }
        float na = fmaxf(__builtin_sqrtf(na2), 1e-8f);
        float nb = fmaxf(__builtin_sqrtf(nb2), 1e-8f);
        stab += dot / (na * nb);
        emer += (an - ap);
    }
    if (lane == 0){
        int o = l * 512 + s;
        float e = emer * 0.5f * (1.0f / 256.0f);
        out[OUT_STAB  + o] = stab * 0.5f;
        out[OUT_EMER  + o] = e;
        out[OUT_DECAY + o] = -e;
    }
}

// ---------------- causal main: per-chunk partials (no atomics) ----------------
__global__ __launch_bounds__(256) void k_causal(
        const float* __restrict__ Aws, const float* __restrict__ wbws,
        const u16* __restrict__ w2b, const float* __restrict__ tgt,
        const float* __restrict__ b2, float* __restrict__ part){
    const int bid = blockIdx.x;
    const int chunk = bid >> 2, q = bid & 3;
    const int i0 = (q & 1) * 128, p0 = (q >> 1) * 128;
    const int tid = threadIdx.x, lane = tid & 63, wid = tid >> 6;
    const int wrow = wid & 1, wcol = wid >> 1;
    const int l15 = lane & 15, quad = lane >> 4;

    __shared__ u16  w2s[128 * 264];
    __shared__ float a_s[256];
    __shared__ float wb_s[256];
    __shared__ float t_s[128];

    {
        int r = tid >> 1, half = tid & 1;
        const uint4* gsrc = (const uint4*)&w2b[(p0 + r) * 256 + half * 128];
        uint4* ldst = (uint4*)&w2s[r * 264 + half * 128];
        for (int j = 0; j < 16; j++) ldst[j] = gsrc[j];
    }
    wb_s[tid] = wbws[tid];

    float bb[4];
    for (int nt = 0; nt < 4; nt++) bb[nt] = b2[p0 + wcol * 64 + nt * 16 + l15];

    f32x4 sig[4][4];
    for (int mt = 0; mt < 4; mt++) for (int nt = 0; nt < 4; nt++)
        sig[mt][nt] = (f32x4){0.f, 0.f, 0.f, 0.f};

    const int ibl = wrow * 64;

    for (int ss = 0; ss < 8; ss++){
        const int bs = chunk * 8 + ss;
        __syncthreads();
        a_s[tid] = Aws[bs * 256 + tid];
        if (tid < 128) t_s[tid] = tgt[bs * 256 + i0 + tid];
        __syncthreads();

        float tv[4];
        for (int mt = 0; mt < 4; mt++) tv[mt] = t_s[ibl + mt * 16 + l15];

        f32x4 acc[4][4];
        for (int mt = 0; mt < 4; mt++) for (int nt = 0; nt < 4; nt++)
            acc[mt][nt] = (f32x4){0.f, 0.f, 0.f, 0.f};

        for (int k = 0; k < 8; k++){
            const int o0 = k * 32 + quad * 8;
            float4 a0 = *(const float4*)&a_s[o0];
            float4 a1 = *(const float4*)&a_s[o0 + 4];
            float4 w0 = *(const float4*)&wb_s[o0];
            float4 w1v = *(const float4*)&wb_s[o0 + 4];
            v8bf bfr[4];
            for (int nt = 0; nt < 4; nt++){
                int pl = wcol * 64 + nt * 16 + l15;
                bfr[nt] = *(const v8bf*)&w2s[pl * 264 + o0];
            }
            for (int mt = 0; mt < 4; mt++){
                float t = tv[mt];
                float e0 = fmaxf(fmaf(t, w0.x,  a0.x), 0.f);
                float e1 = fmaxf(fmaf(t, w0.y,  a0.y), 0.f);
                float e2 = fmaxf(fmaf(t, w0.z,  a0.z), 0.f);
                float e3 = fmaxf(fmaf(t, w0.w,  a0.w), 0.f);
                float e4 = fmaxf(fmaf(t, w1v.x, a1.x), 0.f);
                float e5 = fmaxf(fmaf(t, w1v.y, a1.y), 0.f);
                float e6 = fmaxf(fmaf(t, w1v.z, a1.z), 0.f);
                float e7 = fmaxf(fmaf(t, w1v.w, a1.w), 0.f);
                v8bf afr;
                afr[0] = (__bf16)e0; afr[1] = (__bf16)e1;
                afr[2] = (__bf16)e2; afr[3] = (__bf16)e3;
                afr[4] = (__bf16)e4; afr[5] = (__bf16)e5;
                afr[6] = (__bf16)e6; afr[7] = (__bf16)e7;
                for (int nt = 0; nt < 4; nt++)
                    acc[mt][nt] = mfma16(afr, bfr[nt], acc[mt][nt]);
            }
        }
        for (int mt = 0; mt < 4; mt++)
            for (int nt = 0; nt < 4; nt++)
                for (int r = 0; r < 4; r++)
                    sig[mt][nt][r] += sigmoidf_fast(acc[mt][nt][r] + bb[nt]);
    }

    float* pp = part + (size_t)chunk * 65536;
    for (int mt = 0; mt < 4; mt++)
        for (int r = 0; r < 4; r++){
            int i = i0 + ibl + mt * 16 + quad * 4 + r;
            for (int nt = 0; nt < 4; nt++){
                int p = p0 + wcol * 64 + nt * 16 + l15;
                pp[i * 256 + p] = sig[mt][nt][r];
            }
        }
}

// ---------------- causal reduce ----------------
__global__ void k_creduce(const float* __restrict__ part, float* __restrict__ out){
    const int idx4 = (blockIdx.x * 256 + threadIdx.x) * 4;  // 64 blocks
    float s0 = 0.f, s1 = 0.f, s2 = 0.f, s3 = 0.f;
    for (int c = 0; c < 128; c++){
        float4 v = *(const float4*)&part[(size_t)c * 65536 + idx4];
        s0 += v.x; s1 += v.y; s2 += v.z; s3 += v.w;
    }
    const float sc = 1.0f / 1024.0f;
    float4 r = {s0 * sc, s1 * sc, s2 * sc, s3 * sc};
    *(float4*)&out[OUT_CAUSAL + idx4] = r;
}

// ---------------- gx = x @ Wih^T + bih (parallel over all rows) ----------------
// row r = n*8 + t, n = b*512+s. 512 blocks x 256 threads; wave w covers 192 gates.
__global__ __launch_bounds__(256) void k_gx(
        const float* __restrict__ feat, const u16* __restrict__ wihb,
        const float* __restrict__ bih, float* __restrict__ gxws){
    const int r0 = blockIdx.x * 16;
    const int tid = threadIdx.x, lane = tid & 63, w = tid >> 6;
    const int l15 = lane & 15, quad = lane >> 4;
    const int gbase = w * 192;

    const int r = r0 + l15;
    const int n = r >> 3, t = r & 7;
    const int b = n >> 9, s = n & 511;
    const float* xp = feat + ((size_t)((b * 8 + t) * 512 + s)) * 256;
    v8bf xa[8];
    for (int k = 0; k < 8; k++)
        xa[k] = cvt8(xp + k * 32 + quad * 8);

    f32x4 acc[12];
    for (int nt = 0; nt < 12; nt++) acc[nt] = (f32x4){0.f, 0.f, 0.f, 0.f};
    for (int k = 0; k < 8; k++){
        int d0 = k * 32 + quad * 8;
        for (int nt = 0; nt < 12; nt++){
            int g = gbase + nt * 16 + l15;
            v8bf bfr = *(const v8bf*)&wihb[g * 256 + d0];
            acc[nt] = mfma16(xa[k], bfr, acc[nt]);
        }
    }
    for (int nt = 0; nt < 12; nt++){
        int g = gbase + nt * 16 + l15;
        float bias = bih[g];
        for (int rr = 0; rr < 4; rr++){
            int row = r0 + quad * 4 + rr;
            gxws[(size_t)row * 768 + g] = acc[nt][rr] + bias;
        }
    }
}

// ---------------- sequential GRU: gh-only, weights in VGPRs ----------------
// 64 blocks x 512 thr (8 waves x 96 gates), 16 seqs per block.
__global__ __launch_bounds__(512) void k_gruseq(
        const float* __restrict__ gxws, const u16* __restrict__ whhb,
        const float* __restrict__ bhh, float* __restrict__ out){
    const int n0 = blockIdx.x * 16;
    const int tid = threadIdx.x, lane = tid & 63, wv = tid >> 6;
    const int l15 = lane & 15, quad = lane >> 4;
    const int g0 = wv * 96;

    __shared__ float h_lds[16 * 260];
    __shared__ float g_lds[16 * 776];

    // preload weight tiles 0..2 into VGPRs; tiles 3..5 streamed from L2 each step
    v8bf wreg[3][8];
    for (int nt = 0; nt < 3; nt++)
        for (int k = 0; k < 8; k++)
            wreg[nt][k] = *(const v8bf*)&whhb[(g0 + nt * 16 + l15) * 256 + k * 32 + quad * 8];

    float bias[6];
    for (int nt = 0; nt < 6; nt++) bias[nt] = bhh[g0 + nt * 16 + l15];

    for (int e = tid; e < 16 * 260; e += 512) h_lds[e] = 0.f;

    const int seq = tid >> 5, d0 = (tid & 31) * 8;
    const float* gxbase = gxws + (size_t)(n0 + seq) * 8 * 768 + d0;
    float* evobase = out + OUT_EVO + (size_t)(n0 + seq) * 8 * 256 + d0;
    __syncthreads();

    for (int t = 0; t < 8; t++){
        // ---- gh = h @ Whh^T ----
        v8bf ha[8];
        for (int k = 0; k < 8; k++)
            ha[k] = cvt8(&h_lds[l15 * 260 + k * 32 + quad * 8]);
        f32x4 acc[6];
        for (int nt = 0; nt < 6; nt++) acc[nt] = (f32x4){0.f, 0.f, 0.f, 0.f};
        for (int k = 0; k < 8; k++){
            int dk = k * 32 + quad * 8;
            acc[0] = mfma16(ha[k], wreg[0][k], acc[0]);
            acc[1] = mfma16(ha[k], wreg[1][k], acc[1]);
            acc[2] = mfma16(ha[k], wreg[2][k], acc[2]);
            for (int nt = 3; nt < 6; nt++){
                v8bf bf = *(const v8bf*)&whhb[(g0 + nt * 16 + l15) * 256 + dk];
                acc[nt] = mfma16(ha[k], bf, acc[nt]);
            }
        }
        for (int nt = 0; nt < 6; nt++){
            int g = g0 + nt * 16 + l15;
            for (int rr = 0; rr < 4; rr++)
                g_lds[(quad * 4 + rr) * 776 + g] = acc[nt][rr] + bias[nt];
        }
        // prefetch this step's gx (global, independent of the barrier)
        const float* gxp = gxbase + (size_t)t * 768;
        float4 x0a = *(const float4*)(gxp);
        float4 x0b = *(const float4*)(gxp + 4);
        float4 x1a = *(const float4*)(gxp + 256);
        float4 x1b = *(const float4*)(gxp + 260);
        float4 x2a = *(const float4*)(gxp + 512);
        float4 x2b = *(const float4*)(gxp + 516);
        __syncthreads();
        // ---- pointwise gate update ----
        {
            const float* gh = &g_lds[seq * 776];
            float* hp = &h_lds[seq * 260 + d0];
            float4 g0a = *(const float4*)&gh[d0];
            float4 g0b = *(const float4*)&gh[d0 + 4];
            float4 g1a = *(const float4*)&gh[256 + d0];
            float4 g1b = *(const float4*)&gh[260 + d0];
            float4 g2a = *(const float4*)&gh[512 + d0];
            float4 g2b = *(const float4*)&gh[516 + d0];
            float4 h0 = *(const float4*)hp;
            float4 h1 = *(const float4*)(hp + 4);
            float gxr[8] = {x0a.x, x0a.y, x0a.z, x0a.w, x0b.x, x0b.y, x0b.z, x0b.w};
            float gxz[8] = {x1a.x, x1a.y, x1a.z, x1a.w, x1b.x, x1b.y, x1b.z, x1b.w};
            float gxn[8] = {x2a.x, x2a.y, x2a.z, x2a.w, x2b.x, x2b.y, x2b.z, x2b.w};
            float ghr[8] = {g0a.x, g0a.y, g0a.z, g0a.w, g0b.x, g0b.y, g0b.z, g0b.w};
            float ghz[8] = {g1a.x, g1a.y, g1a.z, g1a.w, g1b.x, g1b.y, g1b.z, g1b.w};
            float ghn[8] = {g2a.x, g2a.y, g2a.z, g2a.w, g2b.x, g2b.y, g2b.z, g2b.w};
            float hold[8] = {h0.x, h0.y, h0.z, h0.w, h1.x, h1.y, h1.z, h1.w};
            float hn[8];
            #pragma unroll
            for (int j = 0; j < 8; j++){
                float r  = sigmoidf_fast(gxr[j] + ghr[j]);
                float z  = sigmoidf_fast(gxz[j] + ghz[j]);
                float nn = tanhf_fast(fmaf(r, ghn[j], gxn[j]));
                hn[j] = (1.f - z) * nn + z * hold[j];
            }
            float4 v0 = {hn[0], hn[1], hn[2], hn[3]};
            float4 v1 = {hn[4], hn[5], hn[6], hn[7]};
            *(float4*)hp       = v0;
            *(float4*)(hp + 4) = v1;
            float* ep = evobase + (size_t)t * 256;
            *(float4*)ep       = v0;
            *(float4*)(ep + 4) = v1;
        }
        __syncthreads();
    }
}

extern "C" void kernel_launch(void* const* d_in, const int* in_sizes, int n_in,
                              void* d_out, int out_size, void* d_ws, size_t ws_size,
                              hipStream_t stream){
    const float* feat = (const float*)d_in[0];
    const float* src  = (const float*)d_in[1];
    const float* tgt  = (const float*)d_in[2];
    const float* Wih  = (const float*)d_in[3];
    const float* Whh  = (const float*)d_in[4];
    const float* bih  = (const float*)d_in[5];
    const float* bhh  = (const float*)d_in[6];
    const float* W1   = (const float*)d_in[7];
    const float* b1   = (const float*)d_in[8];
    const float* W2   = (const float*)d_in[9];
    const float* b2   = (const float*)d_in[10];
    float* out = (float*)d_out;
    char* ws = (char*)d_ws;

    float* wb   = (float*)(ws + WS_WB);
    u16*   wihb = (u16*)(ws + WS_WIHB);
    u16*   whhb = (u16*)(ws + WS_WHHB);
    u16*   w2b  = (u16*)(ws + WS_W2B);
    float* Aws  = (float*)(ws + WS_A);
    float* gxws = (float*)(ws + WS_GX);
    float* part = (float*)(ws + WS_PART);

    k_prep   <<<1793, 256, 0, stream>>>(Wih, Whh, W2, W1, wihb, whhb, w2b, wb);
    k_gx     <<<512,  256, 0, stream>>>(feat, wihb, bih, gxws);
    k_Agemm  <<<64,   256, 0, stream>>>(src, W1, b1, Aws);
    k_metrics<<<3584,  64, 0, stream>>>(feat, out);
    k_causal <<<512,  256, 0, stream>>>(Aws, wb, w2b, tgt, b2, part);
    k_creduce<<<64,   256, 0, stream>>>(part, out);
    k_gruseq <<<64,   512, 0, stream>>>(gxws, whhb, bhh, out);
}

// Round 5
// 269.655 us; speedup vs baseline: 1.4932x; 1.1508x over previous
//
#include <hip/hip_runtime.h>
#include <hip/hip_bf16.h>
#include <stdint.h>

typedef unsigned short u16;
typedef __bf16 v8bf __attribute__((ext_vector_type(8)));
typedef float f32x4 __attribute__((ext_vector_type(4)));

// ws byte offsets
#define WS_WB    0u           // float[256]
#define WS_WIHB  4096u        // u16[196608] -> ends 397312
#define WS_WHHB  397312u      // u16[196608] -> ends 790528
#define WS_W2B   790528u      // u16[65536]  -> ends 921600
#define WS_A     921600u      // float[262144] -> ends 1970176
#define WS_GX    2097152u     // float[8192*768] = 25165824 B -> ends 27262976
#define WS_PART  27262976u    // float[64*65536] = 16777216 B -> ends 44040192

// out (fp32) element offsets
#define OUT_STAB   0
#define OUT_EMER   3584
#define OUT_DECAY  7168
#define OUT_CAUSAL 10752
#define OUT_EVO    76288

__device__ __forceinline__ u16 f2bfu(float f){
    union { float f; uint32_t u; } v; v.f = f;
    uint32_t u = v.u;
    return (u16)((u + 0x7fffu + ((u >> 16) & 1u)) >> 16);
}
__device__ __forceinline__ float sigmoidf_fast(float x){
    float e = __builtin_amdgcn_exp2f(-1.4426950408889634f * x);
    return __builtin_amdgcn_rcpf(1.0f + e);
}
__device__ __forceinline__ float tanhf_fast(float x){
    float e = __builtin_amdgcn_exp2f(-2.8853900817779268f * x);
    return __builtin_amdgcn_rcpf(1.0f + e) * 2.0f - 1.0f;
}
__device__ __forceinline__ f32x4 mfma16(v8bf a, v8bf b, f32x4 c){
    return __builtin_amdgcn_mfma_f32_16x16x32_bf16(a, b, c, 0, 0, 0);
}
__device__ __forceinline__ v8bf cvt8(const float* p){
    float4 a = *(const float4*)p;
    float4 b = *(const float4*)(p + 4);
    v8bf r;
    r[0] = (__bf16)a.x; r[1] = (__bf16)a.y; r[2] = (__bf16)a.z; r[3] = (__bf16)a.w;
    r[4] = (__bf16)b.x; r[5] = (__bf16)b.y; r[6] = (__bf16)b.z; r[7] = (__bf16)b.w;
    return r;
}

// ---------------- prep: bf16 weight copies + wb ----------------
__global__ void k_prep(const float* __restrict__ Wih, const float* __restrict__ Whh,
                       const float* __restrict__ W2,  const float* __restrict__ W1,
                       u16* __restrict__ wihb, u16* __restrict__ whhb,
                       u16* __restrict__ w2b, float* __restrict__ wb){
    int idx = blockIdx.x * 256 + threadIdx.x;   // 1793 blocks
    if (idx < 196608) {
        wihb[idx] = f2bfu(Wih[idx]);
    } else if (idx < 393216) {
        int i = idx - 196608; whhb[i] = f2bfu(Whh[i]);
    } else if (idx < 458752) {
        int i = idx - 393216; w2b[i] = f2bfu(W2[i]);
    } else if (idx < 459008) {
        int o = idx - 458752;
        float s = 0.f;
        const float4* p = (const float4*)&W1[o * 512 + 256];
        for (int j = 0; j < 64; j++){
            float4 v = p[j];
            s += v.x + v.y + v.z + v.w;
        }
        wb[o] = s;
    }
}

// ---------------- A = src @ W1a^T + b1 via MFMA ----------------
__global__ __launch_bounds__(256) void k_Agemm(
        const float* __restrict__ src, const float* __restrict__ W1,
        const float* __restrict__ b1, float* __restrict__ A){
    const int bs0 = blockIdx.x * 16;
    const int tid = threadIdx.x, lane = tid & 63, w = tid >> 6;
    const int l15 = lane & 15, quad = lane >> 4;

    v8bf xa[8];
    for (int k = 0; k < 8; k++)
        xa[k] = cvt8(&src[(bs0 + l15) * 256 + k * 32 + quad * 8]);

    f32x4 acc[4];
    for (int nt = 0; nt < 4; nt++) acc[nt] = (f32x4){0.f, 0.f, 0.f, 0.f};
    for (int k = 0; k < 8; k++){
        int d0 = k * 32 + quad * 8;
        for (int nt = 0; nt < 4; nt++){
            int o = w * 64 + nt * 16 + l15;
            v8bf bfr = cvt8(&W1[o * 512 + d0]);
            acc[nt] = mfma16(xa[k], bfr, acc[nt]);
        }
    }
    for (int nt = 0; nt < 4; nt++){
        int o = w * 64 + nt * 16 + l15;
        float bb = b1[o];
        for (int r = 0; r < 4; r++)
            A[(bs0 + quad * 4 + r) * 256 + o] = acc[nt][r] + bb;
    }
}

// ---------------- stability / emergence / decay ----------------
__global__ void k_metrics(const float* __restrict__ feat, float* __restrict__ out){
    const int bid = blockIdx.x;            // 3584 = 7*512
    const int l = bid >> 9, s = bid & 511;
    const int lane = threadIdx.x;          // 64
    float stab = 0.f, emer = 0.f;
    for (int b = 0; b < 2; b++){
        const float* p = feat + ((size_t)((b * 8 + l) * 512 + s)) * 256;
        const float* n = feat + ((size_t)((b * 8 + l + 1) * 512 + s)) * 256;
        float4 pv = *(const float4*)(p + lane * 4);
        float4 nv = *(const float4*)(n + lane * 4);
        float dot = pv.x * nv.x + pv.y * nv.y + pv.z * nv.z + pv.w * nv.w;
        float na2 = pv.x * pv.x + pv.y * pv.y + pv.z * pv.z + pv.w * pv.w;
        float nb2 = nv.x * nv.x + nv.y * nv.y + nv.z * nv.z + nv.w * nv.w;
        float ap = ((pv.x > 0.1f) ? 1.f : 0.f) + ((pv.y > 0.1f) ? 1.f : 0.f)
                 + ((pv.z > 0.1f) ? 1.f : 0.f) + ((pv.w > 0.1f) ? 1.f : 0.f);
        float an = ((nv.x > 0.1f) ? 1.f : 0.f) + ((nv.y > 0.1f) ? 1.f : 0.f)
                 + ((nv.z > 0.1f) ? 1.f : 0.f) + ((nv.w > 0.1f) ? 1.f : 0.f);
        for (int off = 32; off > 0; off >>= 1){
            dot += __shfl_xor(dot, off);
            na2 += __shfl_xor(na2, off);
            nb2 += __shfl_xor(nb2, off);
            ap  += __shfl_xor(ap,  off);
            an  += __shfl_xor(an,  off);
        }
        float na = fmaxf(__builtin_sqrtf(na2), 1e-8f);
        float nb = fmaxf(__builtin_sqrtf(nb2), 1e-8f);
        stab += dot / (na * nb);
        emer += (an - ap);
    }
    if (lane == 0){
        int o = l * 512 + s;
        float e = emer * 0.5f * (1.0f / 256.0f);
        out[OUT_STAB  + o] = stab * 0.5f;
        out[OUT_EMER  + o] = e;
        out[OUT_DECAY + o] = -e;
    }
}

// ---------------- causal main: 16 samples/block, 64-chunk partials ----------
__global__ __launch_bounds__(256) void k_causal(
        const float* __restrict__ Aws, const float* __restrict__ wbws,
        const u16* __restrict__ w2b, const float* __restrict__ tgt,
        const float* __restrict__ b2, float* __restrict__ part){
    const int bid = blockIdx.x;            // 256 = 64 chunks x 4 quadrants
    const int chunk = bid >> 2, q = bid & 3;
    const int i0 = (q & 1) * 128, p0 = (q >> 1) * 128;
    const int tid = threadIdx.x, lane = tid & 63, wid = tid >> 6;
    const int wrow = wid & 1, wcol = wid >> 1;
    const int l15 = lane & 15, quad = lane >> 4;

    __shared__ u16  w2s[128 * 264];
    __shared__ float a_s[256];
    __shared__ float wb_s[256];
    __shared__ float t_s[128];

    {
        int r = tid >> 1, half = tid & 1;
        const uint4* gsrc = (const uint4*)&w2b[(p0 + r) * 256 + half * 128];
        uint4* ldst = (uint4*)&w2s[r * 264 + half * 128];
        for (int j = 0; j < 16; j++) ldst[j] = gsrc[j];
    }
    wb_s[tid] = wbws[tid];

    float bb[4];
    for (int nt = 0; nt < 4; nt++) bb[nt] = b2[p0 + wcol * 64 + nt * 16 + l15];

    f32x4 sig[4][4];
    for (int mt = 0; mt < 4; mt++) for (int nt = 0; nt < 4; nt++)
        sig[mt][nt] = (f32x4){0.f, 0.f, 0.f, 0.f};

    const int ibl = wrow * 64;

    for (int ss = 0; ss < 16; ss++){
        const int bs = chunk * 16 + ss;
        __syncthreads();
        a_s[tid] = Aws[bs * 256 + tid];
        if (tid < 128) t_s[tid] = tgt[bs * 256 + i0 + tid];
        __syncthreads();

        float tv[4];
        for (int mt = 0; mt < 4; mt++) tv[mt] = t_s[ibl + mt * 16 + l15];

        f32x4 acc[4][4];
        for (int mt = 0; mt < 4; mt++) for (int nt = 0; nt < 4; nt++)
            acc[mt][nt] = (f32x4){0.f, 0.f, 0.f, 0.f};

        for (int k = 0; k < 8; k++){
            const int o0 = k * 32 + quad * 8;
            float4 a0 = *(const float4*)&a_s[o0];
            float4 a1 = *(const float4*)&a_s[o0 + 4];
            float4 w0 = *(const float4*)&wb_s[o0];
            float4 w1v = *(const float4*)&wb_s[o0 + 4];
            v8bf bfr[4];
            for (int nt = 0; nt < 4; nt++){
                int pl = wcol * 64 + nt * 16 + l15;
                bfr[nt] = *(const v8bf*)&w2s[pl * 264 + o0];
            }
            for (int mt = 0; mt < 4; mt++){
                float t = tv[mt];
                float e0 = fmaxf(fmaf(t, w0.x,  a0.x), 0.f);
                float e1 = fmaxf(fmaf(t, w0.y,  a0.y), 0.f);
                float e2 = fmaxf(fmaf(t, w0.z,  a0.z), 0.f);
                float e3 = fmaxf(fmaf(t, w0.w,  a0.w), 0.f);
                float e4 = fmaxf(fmaf(t, w1v.x, a1.x), 0.f);
                float e5 = fmaxf(fmaf(t, w1v.y, a1.y), 0.f);
                float e6 = fmaxf(fmaf(t, w1v.z, a1.z), 0.f);
                float e7 = fmaxf(fmaf(t, w1v.w, a1.w), 0.f);
                v8bf afr;
                afr[0] = (__bf16)e0; afr[1] = (__bf16)e1;
                afr[2] = (__bf16)e2; afr[3] = (__bf16)e3;
                afr[4] = (__bf16)e4; afr[5] = (__bf16)e5;
                afr[6] = (__bf16)e6; afr[7] = (__bf16)e7;
                for (int nt = 0; nt < 4; nt++)
                    acc[mt][nt] = mfma16(afr, bfr[nt], acc[mt][nt]);
            }
        }
        for (int mt = 0; mt < 4; mt++)
            for (int nt = 0; nt < 4; nt++)
                for (int r = 0; r < 4; r++)
                    sig[mt][nt][r] += sigmoidf_fast(acc[mt][nt][r] + bb[nt]);
    }

    float* pp = part + (size_t)chunk * 65536;
    for (int mt = 0; mt < 4; mt++)
        for (int r = 0; r < 4; r++){
            int i = i0 + ibl + mt * 16 + quad * 4 + r;
            for (int nt = 0; nt < 4; nt++){
                int p = p0 + wcol * 64 + nt * 16 + l15;
                pp[i * 256 + p] = sig[mt][nt][r];
            }
        }
}

// ---------------- causal reduce: 256 blocks, coalesced ----------------
__global__ void k_creduce(const float* __restrict__ part, float* __restrict__ out){
    const int idx = blockIdx.x * 256 + threadIdx.x;  // 65536 threads
    float s = 0.f;
    for (int c = 0; c < 64; c++)
        s += part[(size_t)c * 65536 + idx];
    out[OUT_CAUSAL + idx] = s * (1.0f / 1024.0f);
}

// ---------------- gx GEMM: [8192x256] @ wih^T -> [8192x768], LDS-tiled ------
// grid 384 = 64 M-blocks x 6 N-blocks; 256 thr; B-tile (128 gates x 256) in LDS.
__global__ __launch_bounds__(256) void k_gx(
        const float* __restrict__ feat, const u16* __restrict__ wihb,
        const float* __restrict__ bih, float* __restrict__ gxws){
    const int mb = blockIdx.x / 6, nb = blockIdx.x % 6;
    const int tid = threadIdx.x, lane = tid & 63, w = tid >> 6;
    const int l15 = lane & 15, quad = lane >> 4;

    __shared__ u16 blds[128 * 264];

    // stage B-tile: 128 gate rows of wih (bf16), padded stride 264
    {
        int r = tid >> 1, half = tid & 1;
        const uint4* gsrc = (const uint4*)&wihb[(nb * 128 + r) * 256 + half * 128];
        uint4* ldst = (uint4*)&blds[r * 264 + half * 128];
        for (int j = 0; j < 16; j++) ldst[j] = gsrc[j];
    }

    // A fragments direct from global (row-scattered, 32B each, independent)
    v8bf af[2][8];
    for (int mt = 0; mt < 2; mt++){
        int r = mb * 128 + w * 32 + mt * 16 + l15;
        int n = r >> 3, t = r & 7;
        int b = n >> 9, s = n & 511;
        const float* xp = feat + ((size_t)((b * 8 + t) * 512 + s)) * 256;
        for (int kk = 0; kk < 8; kk++)
            af[mt][kk] = cvt8(xp + kk * 32 + quad * 8);
    }
    __syncthreads();

    f32x4 acc[2][8];
    for (int mt = 0; mt < 2; mt++) for (int nt = 0; nt < 8; nt++)
        acc[mt][nt] = (f32x4){0.f, 0.f, 0.f, 0.f};
    for (int kk = 0; kk < 8; kk++){
        int k0 = kk * 32 + quad * 8;
        for (int nt = 0; nt < 8; nt++){
            v8bf bf = *(const v8bf*)&blds[(nt * 16 + l15) * 264 + k0];
            acc[0][nt] = mfma16(af[0][kk], bf, acc[0][nt]);
            acc[1][nt] = mfma16(af[1][kk], bf, acc[1][nt]);
        }
    }
    for (int nt = 0; nt < 8; nt++){
        int g = nb * 128 + nt * 16 + l15;
        float bias = bih[g];
        for (int mt = 0; mt < 2; mt++)
            for (int rr = 0; rr < 4; rr++){
                int row = mb * 128 + w * 32 + mt * 16 + quad * 4 + rr;
                gxws[(size_t)row * 768 + g] = acc[mt][nt][rr] + bias;
            }
    }
}

// ---------------- sequential GRU: gh-only, weights in VGPRs ----------------
__global__ __launch_bounds__(512) void k_gruseq(
        const float* __restrict__ gxws, const u16* __restrict__ whhb,
        const float* __restrict__ bhh, float* __restrict__ out){
    const int n0 = blockIdx.x * 16;
    const int tid = threadIdx.x, lane = tid & 63, wv = tid >> 6;
    const int l15 = lane & 15, quad = lane >> 4;
    const int g0 = wv * 96;

    __shared__ float h_lds[16 * 260];
    __shared__ float g_lds[16 * 776];

    v8bf wreg[3][8];
    for (int nt = 0; nt < 3; nt++)
        for (int k = 0; k < 8; k++)
            wreg[nt][k] = *(const v8bf*)&whhb[(g0 + nt * 16 + l15) * 256 + k * 32 + quad * 8];

    float bias[6];
    for (int nt = 0; nt < 6; nt++) bias[nt] = bhh[g0 + nt * 16 + l15];

    for (int e = tid; e < 16 * 260; e += 512) h_lds[e] = 0.f;

    const int seq = tid >> 5, d0 = (tid & 31) * 8;
    const float* gxbase = gxws + (size_t)(n0 + seq) * 8 * 768 + d0;
    float* evobase = out + OUT_EVO + (size_t)(n0 + seq) * 8 * 256 + d0;
    __syncthreads();

    for (int t = 0; t < 8; t++){
        v8bf ha[8];
        for (int k = 0; k < 8; k++)
            ha[k] = cvt8(&h_lds[l15 * 260 + k * 32 + quad * 8]);
        f32x4 acc[6];
        for (int nt = 0; nt < 6; nt++) acc[nt] = (f32x4){0.f, 0.f, 0.f, 0.f};
        for (int k = 0; k < 8; k++){
            int dk = k * 32 + quad * 8;
            acc[0] = mfma16(ha[k], wreg[0][k], acc[0]);
            acc[1] = mfma16(ha[k], wreg[1][k], acc[1]);
            acc[2] = mfma16(ha[k], wreg[2][k], acc[2]);
            for (int nt = 3; nt < 6; nt++){
                v8bf bf = *(const v8bf*)&whhb[(g0 + nt * 16 + l15) * 256 + dk];
                acc[nt] = mfma16(ha[k], bf, acc[nt]);
            }
        }
        for (int nt = 0; nt < 6; nt++){
            int g = g0 + nt * 16 + l15;
            for (int rr = 0; rr < 4; rr++)
                g_lds[(quad * 4 + rr) * 776 + g] = acc[nt][rr] + bias[nt];
        }
        const float* gxp = gxbase + (size_t)t * 768;
        float4 x0a = *(const float4*)(gxp);
        float4 x0b = *(const float4*)(gxp + 4);
        float4 x1a = *(const float4*)(gxp + 256);
        float4 x1b = *(const float4*)(gxp + 260);
        float4 x2a = *(const float4*)(gxp + 512);
        float4 x2b = *(const float4*)(gxp + 516);
        __syncthreads();
        {
            const float* gh = &g_lds[seq * 776];
            float* hp = &h_lds[seq * 260 + d0];
            float4 g0a = *(const float4*)&gh[d0];
            float4 g0b = *(const float4*)&gh[d0 + 4];
            float4 g1a = *(const float4*)&gh[256 + d0];
            float4 g1b = *(const float4*)&gh[260 + d0];
            float4 g2a = *(const float4*)&gh[512 + d0];
            float4 g2b = *(const float4*)&gh[516 + d0];
            float4 h0 = *(const float4*)hp;
            float4 h1 = *(const float4*)(hp + 4);
            float gxr[8] = {x0a.x, x0a.y, x0a.z, x0a.w, x0b.x, x0b.y, x0b.z, x0b.w};
            float gxz[8] = {x1a.x, x1a.y, x1a.z, x1a.w, x1b.x, x1b.y, x1b.z, x1b.w};
            float gxn[8] = {x2a.x, x2a.y, x2a.z, x2a.w, x2b.x, x2b.y, x2b.z, x2b.w};
            float ghr[8] = {g0a.x, g0a.y, g0a.z, g0a.w, g0b.x, g0b.y, g0b.z, g0b.w};
            float ghz[8] = {g1a.x, g1a.y, g1a.z, g1a.w, g1b.x, g1b.y, g1b.z, g1b.w};
            float ghn[8] = {g2a.x, g2a.y, g2a.z, g2a.w, g2b.x, g2b.y, g2b.z, g2b.w};
            float hold[8] = {h0.x, h0.y, h0.z, h0.w, h1.x, h1.y, h1.z, h1.w};
            float hn[8];
            #pragma unroll
            for (int j = 0; j < 8; j++){
                float r  = sigmoidf_fast(gxr[j] + ghr[j]);
                float z  = sigmoidf_fast(gxz[j] + ghz[j]);
                float nn = tanhf_fast(fmaf(r, ghn[j], gxn[j]));
                hn[j] = (1.f - z) * nn + z * hold[j];
            }
            float4 v0 = {hn[0], hn[1], hn[2], hn[3]};
            float4 v1 = {hn[4], hn[5], hn[6], hn[7]};
            *(float4*)hp       = v0;
            *(float4*)(hp + 4) = v1;
            float* ep = evobase + (size_t)t * 256;
            *(float4*)ep       = v0;
            *(float4*)(ep + 4) = v1;
        }
        __syncthreads();
    }
}

extern "C" void kernel_launch(void* const* d_in, const int* in_sizes, int n_in,
                              void* d_out, int out_size, void* d_ws, size_t ws_size,
                              hipStream_t stream){
    const float* feat = (const float*)d_in[0];
    const float* src  = (const float*)d_in[1];
    const float* tgt  = (const float*)d_in[2];
    const float* Wih  = (const float*)d_in[3];
    const float* Whh  = (const float*)d_in[4];
    const float* bih  = (const float*)d_in[5];
    const float* bhh  = (const float*)d_in[6];
    const float* W1   = (const float*)d_in[7];
    const float* b1   = (const float*)d_in[8];
    const float* W2   = (const float*)d_in[9];
    const float* b2   = (const float*)d_in[10];
    float* out = (float*)d_out;
    char* ws = (char*)d_ws;

    float* wb   = (float*)(ws + WS_WB);
    u16*   wihb = (u16*)(ws + WS_WIHB);
    u16*   whhb = (u16*)(ws + WS_WHHB);
    u16*   w2b  = (u16*)(ws + WS_W2B);
    float* Aws  = (float*)(ws + WS_A);
    float* gxws = (float*)(ws + WS_GX);
    float* part = (float*)(ws + WS_PART);

    k_prep   <<<1793, 256, 0, stream>>>(Wih, Whh, W2, W1, wihb, whhb, w2b, wb);
    k_gx     <<<384,  256, 0, stream>>>(feat, wihb, bih, gxws);
    k_Agemm  <<<64,   256, 0, stream>>>(src, W1, b1, Aws);
    k_metrics<<<3584,  64, 0, stream>>>(feat, out);
    k_causal <<<256,  256, 0, stream>>>(Aws, wb, w2b, tgt, b2, part);
    k_creduce<<<256,  256, 0, stream>>>(part, out);
    k_gruseq <<<64,   512, 0, stream>>>(gxws, whhb, bhh, out);
}

// Round 6
// 246.759 us; speedup vs baseline: 1.6317x; 1.0928x over previous
//
#include <hip/hip_runtime.h>
#include <hip/hip_bf16.h>
#include <stdint.h>

typedef unsigned short u16;
typedef __bf16 v8bf __attribute__((ext_vector_type(8)));
typedef float f32x4 __attribute__((ext_vector_type(4)));

// ws byte offsets (ends at 60817408 — layout size proven in round 1)
#define WS_WB    0u           // float[256]
#define WS_WIHB  4096u        // u16[196608] -> ends 397312
#define WS_WHHB  397312u      // u16[196608] -> ends 790528
#define WS_W2B   790528u      // u16[65536]  -> ends 921600
#define WS_A     921600u      // float[262144] -> ends 1970176
#define WS_GX    2097152u     // float[8192*768] -> ends 27262976
#define WS_PART  27262976u    // float[128*65536] = 33.5 MB -> ends 60817408

// out (fp32) element offsets
#define OUT_STAB   0
#define OUT_EMER   3584
#define OUT_DECAY  7168
#define OUT_CAUSAL 10752
#define OUT_EVO    76288

__device__ __forceinline__ u16 f2bfu(float f){
    union { float f; uint32_t u; } v; v.f = f;
    uint32_t u = v.u;
    return (u16)((u + 0x7fffu + ((u >> 16) & 1u)) >> 16);
}
__device__ __forceinline__ float sigmoidf_fast(float x){
    float e = __builtin_amdgcn_exp2f(-1.4426950408889634f * x);
    return __builtin_amdgcn_rcpf(1.0f + e);
}
__device__ __forceinline__ float tanhf_fast(float x){
    float e = __builtin_amdgcn_exp2f(-2.8853900817779268f * x);
    return __builtin_amdgcn_rcpf(1.0f + e) * 2.0f - 1.0f;
}
__device__ __forceinline__ f32x4 mfma16(v8bf a, v8bf b, f32x4 c){
    return __builtin_amdgcn_mfma_f32_16x16x32_bf16(a, b, c, 0, 0, 0);
}
__device__ __forceinline__ v8bf cvt8(const float* p){
    float4 a = *(const float4*)p;
    float4 b = *(const float4*)(p + 4);
    v8bf r;
    r[0] = (__bf16)a.x; r[1] = (__bf16)a.y; r[2] = (__bf16)a.z; r[3] = (__bf16)a.w;
    r[4] = (__bf16)b.x; r[5] = (__bf16)b.y; r[6] = (__bf16)b.z; r[7] = (__bf16)b.w;
    return r;
}

// ---------------- prep: bf16 weight copies + wb ----------------
__global__ void k_prep(const float* __restrict__ Wih, const float* __restrict__ Whh,
                       const float* __restrict__ W2,  const float* __restrict__ W1,
                       u16* __restrict__ wihb, u16* __restrict__ whhb,
                       u16* __restrict__ w2b, float* __restrict__ wb){
    int idx = blockIdx.x * 256 + threadIdx.x;   // 1793 blocks
    if (idx < 196608) {
        wihb[idx] = f2bfu(Wih[idx]);
    } else if (idx < 393216) {
        int i = idx - 196608; whhb[i] = f2bfu(Whh[i]);
    } else if (idx < 458752) {
        int i = idx - 393216; w2b[i] = f2bfu(W2[i]);
    } else if (idx < 459008) {
        int o = idx - 458752;
        float s = 0.f;
        const float4* p = (const float4*)&W1[o * 512 + 256];
        for (int j = 0; j < 64; j++){
            float4 v = p[j];
            s += v.x + v.y + v.z + v.w;
        }
        wb[o] = s;
    }
}

// ---------------- A = src @ W1a^T + b1 via MFMA ----------------
__global__ __launch_bounds__(256) void k_Agemm(
        const float* __restrict__ src, const float* __restrict__ W1,
        const float* __restrict__ b1, float* __restrict__ A){
    const int bs0 = blockIdx.x * 16;
    const int tid = threadIdx.x, lane = tid & 63, w = tid >> 6;
    const int l15 = lane & 15, quad = lane >> 4;

    v8bf xa[8];
    for (int k = 0; k < 8; k++)
        xa[k] = cvt8(&src[(bs0 + l15) * 256 + k * 32 + quad * 8]);

    f32x4 acc[4];
    for (int nt = 0; nt < 4; nt++) acc[nt] = (f32x4){0.f, 0.f, 0.f, 0.f};
    for (int k = 0; k < 8; k++){
        int d0 = k * 32 + quad * 8;
        for (int nt = 0; nt < 4; nt++){
            int o = w * 64 + nt * 16 + l15;
            v8bf bfr = cvt8(&W1[o * 512 + d0]);
            acc[nt] = mfma16(xa[k], bfr, acc[nt]);
        }
    }
    for (int nt = 0; nt < 4; nt++){
        int o = w * 64 + nt * 16 + l15;
        float bb = b1[o];
        for (int r = 0; r < 4; r++)
            A[(bs0 + quad * 4 + r) * 256 + o] = acc[nt][r] + bb;
    }
}

// ---------------- stability / emergence / decay ----------------
__global__ void k_metrics(const float* __restrict__ feat, float* __restrict__ out){
    const int bid = blockIdx.x;            // 3584 = 7*512
    const int l = bid >> 9, s = bid & 511;
    const int lane = threadIdx.x;          // 64
    float stab = 0.f, emer = 0.f;
    for (int b = 0; b < 2; b++){
        const float* p = feat + ((size_t)((b * 8 + l) * 512 + s)) * 256;
        const float* n = feat + ((size_t)((b * 8 + l + 1) * 512 + s)) * 256;
        float4 pv = *(const float4*)(p + lane * 4);
        float4 nv = *(const float4*)(n + lane * 4);
        float dot = pv.x * nv.x + pv.y * nv.y + pv.z * nv.z + pv.w * nv.w;
        float na2 = pv.x * pv.x + pv.y * pv.y + pv.z * pv.z + pv.w * pv.w;
        float nb2 = nv.x * nv.x + nv.y * nv.y + nv.z * nv.z + nv.w * nv.w;
        float ap = ((pv.x > 0.1f) ? 1.f : 0.f) + ((pv.y > 0.1f) ? 1.f : 0.f)
                 + ((pv.z > 0.1f) ? 1.f : 0.f) + ((pv.w > 0.1f) ? 1.f : 0.f);
        float an = ((nv.x > 0.1f) ? 1.f : 0.f) + ((nv.y > 0.1f) ? 1.f : 0.f)
                 + ((nv.z > 0.1f) ? 1.f : 0.f) + ((nv.w > 0.1f) ? 1.f : 0.f);
        for (int off = 32; off > 0; off >>= 1){
            dot += __shfl_xor(dot, off);
            na2 += __shfl_xor(na2, off);
            nb2 += __shfl_xor(nb2, off);
            ap  += __shfl_xor(ap,  off);
            an  += __shfl_xor(an,  off);
        }
        float na = fmaxf(__builtin_sqrtf(na2), 1e-8f);
        float nb = fmaxf(__builtin_sqrtf(nb2), 1e-8f);
        stab += dot / (na * nb);
        emer += (an - ap);
    }
    if (lane == 0){
        int o = l * 512 + s;
        float e = emer * 0.5f * (1.0f / 256.0f);
        out[OUT_STAB  + o] = stab * 0.5f;
        out[OUT_EMER  + o] = e;
        out[OUT_DECAY + o] = -e;
    }
}

// ---------------- causal main: 4 waves stacked on i, no dup h-construct -----
// grid 512 = 128 chunks x 4 quadrants; 8 samples/chunk; 2 blocks/CU.
// wave w covers i in [i0+w*32, +32) x all 128 p of [p0, p0+128).
__global__ __launch_bounds__(256, 2) void k_causal(
        const float* __restrict__ Aws, const float* __restrict__ wbws,
        const u16* __restrict__ w2b, const float* __restrict__ tgt,
        const float* __restrict__ b2, float* __restrict__ part){
    const int bid = blockIdx.x;
    const int chunk = bid >> 2, q = bid & 3;
    const int i0 = (q & 1) * 128, p0 = (q >> 1) * 128;
    const int tid = threadIdx.x, lane = tid & 63, w = tid >> 6;
    const int l15 = lane & 15, quad = lane >> 4;

    __shared__ u16  w2s[128 * 264];
    __shared__ float a_s[256];
    __shared__ float wb_s[256];
    __shared__ float t_s[128];

    {
        int r = tid >> 1, half = tid & 1;
        const uint4* gsrc = (const uint4*)&w2b[(p0 + r) * 256 + half * 128];
        uint4* ldst = (uint4*)&w2s[r * 264 + half * 128];
        for (int j = 0; j < 16; j++) ldst[j] = gsrc[j];
    }
    wb_s[tid] = wbws[tid];

    float bb[8];
    for (int nt = 0; nt < 8; nt++) bb[nt] = b2[p0 + nt * 16 + l15];

    f32x4 sig[2][8];
    for (int mt = 0; mt < 2; mt++) for (int nt = 0; nt < 8; nt++)
        sig[mt][nt] = (f32x4){0.f, 0.f, 0.f, 0.f};

    for (int ss = 0; ss < 8; ss++){
        const int bs = chunk * 8 + ss;
        __syncthreads();
        a_s[tid] = Aws[bs * 256 + tid];
        if (tid < 128) t_s[tid] = tgt[bs * 256 + i0 + tid];
        __syncthreads();

        float tv[2];
        for (int mt = 0; mt < 2; mt++) tv[mt] = t_s[w * 32 + mt * 16 + l15];

        f32x4 acc[2][8];
        for (int mt = 0; mt < 2; mt++) for (int nt = 0; nt < 8; nt++)
            acc[mt][nt] = (f32x4){0.f, 0.f, 0.f, 0.f};

        for (int k = 0; k < 8; k++){
            const int o0 = k * 32 + quad * 8;
            float4 a0 = *(const float4*)&a_s[o0];
            float4 a1 = *(const float4*)&a_s[o0 + 4];
            float4 w0 = *(const float4*)&wb_s[o0];
            float4 w1v = *(const float4*)&wb_s[o0 + 4];
            v8bf afr[2];
            for (int mt = 0; mt < 2; mt++){
                float t = tv[mt];
                float e0 = fmaxf(fmaf(t, w0.x,  a0.x), 0.f);
                float e1 = fmaxf(fmaf(t, w0.y,  a0.y), 0.f);
                float e2 = fmaxf(fmaf(t, w0.z,  a0.z), 0.f);
                float e3 = fmaxf(fmaf(t, w0.w,  a0.w), 0.f);
                float e4 = fmaxf(fmaf(t, w1v.x, a1.x), 0.f);
                float e5 = fmaxf(fmaf(t, w1v.y, a1.y), 0.f);
                float e6 = fmaxf(fmaf(t, w1v.z, a1.z), 0.f);
                float e7 = fmaxf(fmaf(t, w1v.w, a1.w), 0.f);
                v8bf af;
                af[0] = (__bf16)e0; af[1] = (__bf16)e1;
                af[2] = (__bf16)e2; af[3] = (__bf16)e3;
                af[4] = (__bf16)e4; af[5] = (__bf16)e5;
                af[6] = (__bf16)e6; af[7] = (__bf16)e7;
                afr[mt] = af;
            }
            for (int nt = 0; nt < 8; nt++){
                v8bf bfr = *(const v8bf*)&w2s[(nt * 16 + l15) * 264 + o0];
                acc[0][nt] = mfma16(afr[0], bfr, acc[0][nt]);
                acc[1][nt] = mfma16(afr[1], bfr, acc[1][nt]);
            }
        }
        for (int mt = 0; mt < 2; mt++)
            for (int nt = 0; nt < 8; nt++)
                for (int r = 0; r < 4; r++)
                    sig[mt][nt][r] += sigmoidf_fast(acc[mt][nt][r] + bb[nt]);
    }

    float* pp = part + (size_t)chunk * 65536;
    for (int mt = 0; mt < 2; mt++)
        for (int r = 0; r < 4; r++){
            int i = i0 + w * 32 + mt * 16 + quad * 4 + r;
            for (int nt = 0; nt < 8; nt++){
                int p = p0 + nt * 16 + l15;
                pp[i * 256 + p] = sig[mt][nt][r];
            }
        }
}

// ---------------- causal reduce: 256 blocks, coalesced ----------------
__global__ void k_creduce(const float* __restrict__ part, float* __restrict__ out){
    const int idx = blockIdx.x * 256 + threadIdx.x;  // 65536 threads
    float s = 0.f;
    for (int c = 0; c < 128; c++)
        s += part[(size_t)c * 65536 + idx];
    out[OUT_CAUSAL + idx] = s * (1.0f / 1024.0f);
}

// ---------------- gx GEMM: [8192x256] @ wih^T -> [8192x768], LDS-tiled ------
__global__ __launch_bounds__(256) void k_gx(
        const float* __restrict__ feat, const u16* __restrict__ wihb,
        const float* __restrict__ bih, float* __restrict__ gxws){
    const int mb = blockIdx.x / 6, nb = blockIdx.x % 6;
    const int tid = threadIdx.x, lane = tid & 63, w = tid >> 6;
    const int l15 = lane & 15, quad = lane >> 4;

    __shared__ u16 blds[128 * 264];

    {
        int r = tid >> 1, half = tid & 1;
        const uint4* gsrc = (const uint4*)&wihb[(nb * 128 + r) * 256 + half * 128];
        uint4* ldst = (uint4*)&blds[r * 264 + half * 128];
        for (int j = 0; j < 16; j++) ldst[j] = gsrc[j];
    }

    v8bf af[2][8];
    for (int mt = 0; mt < 2; mt++){
        int r = mb * 128 + w * 32 + mt * 16 + l15;
        int n = r >> 3, t = r & 7;
        int b = n >> 9, s = n & 511;
        const float* xp = feat + ((size_t)((b * 8 + t) * 512 + s)) * 256;
        for (int kk = 0; kk < 8; kk++)
            af[mt][kk] = cvt8(xp + kk * 32 + quad * 8);
    }
    __syncthreads();

    f32x4 acc[2][8];
    for (int mt = 0; mt < 2; mt++) for (int nt = 0; nt < 8; nt++)
        acc[mt][nt] = (f32x4){0.f, 0.f, 0.f, 0.f};
    for (int kk = 0; kk < 8; kk++){
        int k0 = kk * 32 + quad * 8;
        for (int nt = 0; nt < 8; nt++){
            v8bf bf = *(const v8bf*)&blds[(nt * 16 + l15) * 264 + k0];
            acc[0][nt] = mfma16(af[0][kk], bf, acc[0][nt]);
            acc[1][nt] = mfma16(af[1][kk], bf, acc[1][nt]);
        }
    }
    for (int nt = 0; nt < 8; nt++){
        int g = nb * 128 + nt * 16 + l15;
        float bias = bih[g];
        for (int mt = 0; mt < 2; mt++)
            for (int rr = 0; rr < 4; rr++){
                int row = mb * 128 + w * 32 + mt * 16 + quad * 4 + rr;
                gxws[(size_t)row * 768 + g] = acc[mt][nt][rr] + bias;
            }
    }
}

// ---------------- sequential GRU: gh-only, weights in VGPRs ----------------
__global__ __launch_bounds__(512) void k_gruseq(
        const float* __restrict__ gxws, const u16* __restrict__ whhb,
        const float* __restrict__ bhh, float* __restrict__ out){
    const int n0 = blockIdx.x * 16;
    const int tid = threadIdx.x, lane = tid & 63, wv = tid >> 6;
    const int l15 = lane & 15, quad = lane >> 4;
    const int g0 = wv * 96;

    __shared__ float h_lds[16 * 260];
    __shared__ float g_lds[16 * 776];

    v8bf wreg[3][8];
    for (int nt = 0; nt < 3; nt++)
        for (int k = 0; k < 8; k++)
            wreg[nt][k] = *(const v8bf*)&whhb[(g0 + nt * 16 + l15) * 256 + k * 32 + quad * 8];

    float bias[6];
    for (int nt = 0; nt < 6; nt++) bias[nt] = bhh[g0 + nt * 16 + l15];

    for (int e = tid; e < 16 * 260; e += 512) h_lds[e] = 0.f;

    const int seq = tid >> 5, d0 = (tid & 31) * 8;
    const float* gxbase = gxws + (size_t)(n0 + seq) * 8 * 768 + d0;
    float* evobase = out + OUT_EVO + (size_t)(n0 + seq) * 8 * 256 + d0;
    __syncthreads();

    for (int t = 0; t < 8; t++){
        v8bf ha[8];
        for (int k = 0; k < 8; k++)
            ha[k] = cvt8(&h_lds[l15 * 260 + k * 32 + quad * 8]);
        f32x4 acc[6];
        for (int nt = 0; nt < 6; nt++) acc[nt] = (f32x4){0.f, 0.f, 0.f, 0.f};
        for (int k = 0; k < 8; k++){
            int dk = k * 32 + quad * 8;
            acc[0] = mfma16(ha[k], wreg[0][k], acc[0]);
            acc[1] = mfma16(ha[k], wreg[1][k], acc[1]);
            acc[2] = mfma16(ha[k], wreg[2][k], acc[2]);
            for (int nt = 3; nt < 6; nt++){
                v8bf bf = *(const v8bf*)&whhb[(g0 + nt * 16 + l15) * 256 + dk];
                acc[nt] = mfma16(ha[k], bf, acc[nt]);
            }
        }
        for (int nt = 0; nt < 6; nt++){
            int g = g0 + nt * 16 + l15;
            for (int rr = 0; rr < 4; rr++)
                g_lds[(quad * 4 + rr) * 776 + g] = acc[nt][rr] + bias[nt];
        }
        const float* gxp = gxbase + (size_t)t * 768;
        float4 x0a = *(const float4*)(gxp);
        float4 x0b = *(const float4*)(gxp + 4);
        float4 x1a = *(const float4*)(gxp + 256);
        float4 x1b = *(const float4*)(gxp + 260);
        float4 x2a = *(const float4*)(gxp + 512);
        float4 x2b = *(const float4*)(gxp + 516);
        __syncthreads();
        {
            const float* gh = &g_lds[seq * 776];
            float* hp = &h_lds[seq * 260 + d0];
            float4 g0a = *(const float4*)&gh[d0];
            float4 g0b = *(const float4*)&gh[d0 + 4];
            float4 g1a = *(const float4*)&gh[256 + d0];
            float4 g1b = *(const float4*)&gh[260 + d0];
            float4 g2a = *(const float4*)&gh[512 + d0];
            float4 g2b = *(const float4*)&gh[516 + d0];
            float4 h0 = *(const float4*)hp;
            float4 h1 = *(const float4*)(hp + 4);
            float gxr[8] = {x0a.x, x0a.y, x0a.z, x0a.w, x0b.x, x0b.y, x0b.z, x0b.w};
            float gxz[8] = {x1a.x, x1a.y, x1a.z, x1a.w, x1b.x, x1b.y, x1b.z, x1b.w};
            float gxn[8] = {x2a.x, x2a.y, x2a.z, x2a.w, x2b.x, x2b.y, x2b.z, x2b.w};
            float ghr[8] = {g0a.x, g0a.y, g0a.z, g0a.w, g0b.x, g0b.y, g0b.z, g0b.w};
            float ghz[8] = {g1a.x, g1a.y, g1a.z, g1a.w, g1b.x, g1b.y, g1b.z, g1b.w};
            float ghn[8] = {g2a.x, g2a.y, g2a.z, g2a.w, g2b.x, g2b.y, g2b.z, g2b.w};
            float hold[8] = {h0.x, h0.y, h0.z, h0.w, h1.x, h1.y, h1.z, h1.w};
            float hn[8];
            #pragma unroll
            for (int j = 0; j < 8; j++){
                float r  = sigmoidf_fast(gxr[j] + ghr[j]);
                float z  = sigmoidf_fast(gxz[j] + ghz[j]);
                float nn = tanhf_fast(fmaf(r, ghn[j], gxn[j]));
                hn[j] = (1.f - z) * nn + z * hold[j];
            }
            float4 v0 = {hn[0], hn[1], hn[2], hn[3]};
            float4 v1 = {hn[4], hn[5], hn[6], hn[7]};
            *(float4*)hp       = v0;
            *(float4*)(hp + 4) = v1;
            float* ep = evobase + (size_t)t * 256;
            *(float4*)ep       = v0;
            *(float4*)(ep + 4) = v1;
        }
        __syncthreads();
    }
}

extern "C" void kernel_launch(void* const* d_in, const int* in_sizes, int n_in,
                              void* d_out, int out_size, void* d_ws, size_t ws_size,
                              hipStream_t stream){
    const float* feat = (const float*)d_in[0];
    const float* src  = (const float*)d_in[1];
    const float* tgt  = (const float*)d_in[2];
    const float* Wih  = (const float*)d_in[3];
    const float* Whh  = (const float*)d_in[4];
    const float* bih  = (const float*)d_in[5];
    const float* bhh  = (const float*)d_in[6];
    const float* W1   = (const float*)d_in[7];
    const float* b1   = (const float*)d_in[8];
    const float* W2   = (const float*)d_in[9];
    const float* b2   = (const float*)d_in[10];
    float* out = (float*)d_out;
    char* ws = (char*)d_ws;

    float* wb   = (float*)(ws + WS_WB);
    u16*   wihb = (u16*)(ws + WS_WIHB);
    u16*   whhb = (u16*)(ws + WS_WHHB);
    u16*   w2b  = (u16*)(ws + WS_W2B);
    float* Aws  = (float*)(ws + WS_A);
    float* gxws = (float*)(ws + WS_GX);
    float* part = (float*)(ws + WS_PART);

    k_prep   <<<1793, 256, 0, stream>>>(Wih, Whh, W2, W1, wihb, whhb, w2b, wb);
    k_gx     <<<384,  256, 0, stream>>>(feat, wihb, bih, gxws);
    k_Agemm  <<<64,   256, 0, stream>>>(src, W1, b1, Aws);
    k_metrics<<<3584,  64, 0, stream>>>(feat, out);
    k_causal <<<512,  256, 0, stream>>>(Aws, wb, w2b, tgt, b2, part);
    k_creduce<<<256,  256, 0, stream>>>(part, out);
    k_gruseq <<<64,   512, 0, stream>>>(gxws, whhb, bhh, out);
}